// Round 1
// baseline (518.970 us; speedup 1.0000x reference)
//
#include <hip/hip_runtime.h>

#define LRELU(x) ((x) > 0.f ? (x) : 0.01f * (x))

// Order-preserving float->uint encoding for atomicMax on floats.
__device__ __forceinline__ unsigned enc_f(float f) {
    unsigned u = __float_as_uint(f);
    return (u & 0x80000000u) ? ~u : (u | 0x80000000u);
}
__device__ __forceinline__ float dec_f(unsigned u) {
    unsigned v = (u & 0x80000000u) ? (u & 0x7FFFFFFFu) : ~u;
    return __uint_as_float(v);
}

// hw[n, c] = dot(h[n, :], Ww[:, c]) + bw[c]   (N x 128) @ (128 x 64)
// 8 rows per wave; each thread: 2 cols x 4 rows. Ww staged in LDS.
__global__ __launch_bounds__(256) void k_proj(
    const float* __restrict__ h, const float* __restrict__ Ww,
    const float* __restrict__ bw, float* __restrict__ hw, int n_nodes)
{
    __shared__ float ws[128 * 64];
#pragma unroll
    for (int i = 0; i < 32; ++i)
        ws[i * 256 + threadIdx.x] = Ww[i * 256 + threadIdx.x];
    __syncthreads();

    const int lane = threadIdx.x & 63;
    const int wid  = threadIdx.x >> 6;
    const int cp   = lane & 31;   // column pair: cols 2cp, 2cp+1
    const int rsub = lane >> 5;   // 0/1: which 4-row half of the 8-row group
    const int row0 = (blockIdx.x * 4 + wid) * 8 + rsub * 4;
    if (row0 >= n_nodes) return;  // N % 8 == 0 in this problem

    float acc[4][2] = {{0.f,0.f},{0.f,0.f},{0.f,0.f},{0.f,0.f}};
    const float* hrow = h + (size_t)row0 * 128;

    for (int k = 0; k < 128; k += 4) {
        float ha[4][4];
#pragma unroll
        for (int r = 0; r < 4; ++r)
            *(float4*)ha[r] = *(const float4*)(hrow + r * 128 + k);
#pragma unroll
        for (int kk = 0; kk < 4; ++kk) {
            float2 w2 = *(const float2*)(&ws[(k + kk) * 64 + cp * 2]);
#pragma unroll
            for (int r = 0; r < 4; ++r) {
                acc[r][0] = __fmaf_rn(ha[r][kk], w2.x, acc[r][0]);
                acc[r][1] = __fmaf_rn(ha[r][kk], w2.y, acc[r][1]);
            }
        }
    }
    const float b0 = bw[cp * 2], b1 = bw[cp * 2 + 1];
#pragma unroll
    for (int r = 0; r < 4; ++r) {
        float2 o;
        o.x = acc[r][0] + b0;
        o.y = acc[r][1] + b1;
        *(float2*)(hw + (size_t)(row0 + r) * 64 + cp * 2) = o;
    }
}

// Per (node, head): a_src = <hw[n,h,:], Wa[0:16]>, a_dst = <hw[n,h,:], Wa[16:32]>
// Also initializes m_enc (encoded -inf == 0) and denom.
__global__ __launch_bounds__(256) void k_node(
    const float* __restrict__ hw, const float* __restrict__ Wa,
    float* __restrict__ asrc, float* __restrict__ adst,
    unsigned* __restrict__ m_enc, float* __restrict__ denom, int n4)
{
    int i = blockIdx.x * 256 + threadIdx.x;
    if (i >= n4) return;
    const float* hp = hw + (size_t)i * 16;  // (n*4+hd)*16 == n*64 + hd*16
    float as = 0.f, ad = 0.f;
#pragma unroll
    for (int j = 0; j < 16; ++j) {
        float v = hp[j];
        as = __fmaf_rn(v, Wa[j], as);
        ad = __fmaf_rn(v, Wa[16 + j], ad);
    }
    asrc[i] = as;
    adst[i] = ad;
    m_enc[i] = 0u;     // encodes "less than any finite float"
    denom[i] = 0.f;
}

__global__ __launch_bounds__(256) void k_edge_max(
    const int* __restrict__ src, const int* __restrict__ dst,
    const float* __restrict__ asrc, const float* __restrict__ adst,
    const float* __restrict__ ba_p, unsigned* __restrict__ m_enc, int n_edges)
{
    int e = blockIdx.x * 256 + threadIdx.x;
    if (e >= n_edges) return;
    const float ba = *ba_p;
    int s = src[e], d = dst[e];
    float4 av = *(const float4*)(asrc + (size_t)s * 4);
    float4 dv = *(const float4*)(adst + (size_t)d * 4);
    const float* ap = (const float*)&av;
    const float* dp = (const float*)&dv;
#pragma unroll
    for (int hd = 0; hd < 4; ++hd) {
        float a = ap[hd] + dp[hd] + ba;
        a = LRELU(a);
        atomicMax(m_enc + (size_t)d * 4 + hd, enc_f(a));
    }
}

__global__ __launch_bounds__(256) void k_edge_sum(
    const int* __restrict__ src, const int* __restrict__ dst,
    const float* __restrict__ asrc, const float* __restrict__ adst,
    const float* __restrict__ ba_p, const unsigned* __restrict__ m_enc,
    float* __restrict__ denom, int n_edges)
{
    int e = blockIdx.x * 256 + threadIdx.x;
    if (e >= n_edges) return;
    const float ba = *ba_p;
    int s = src[e], d = dst[e];
    float4 av = *(const float4*)(asrc + (size_t)s * 4);
    float4 dv = *(const float4*)(adst + (size_t)d * 4);
    const float* ap = (const float*)&av;
    const float* dp = (const float*)&dv;
#pragma unroll
    for (int hd = 0; hd < 4; ++hd) {
        float a = ap[hd] + dp[hd] + ba;
        a = LRELU(a);
        float m = dec_f(m_enc[(size_t)d * 4 + hd]);
        atomicAdd(denom + (size_t)d * 4 + hd, __expf(a - m));
    }
}

// One thread per (edge, output col). 64 lanes of a wave share one edge.
__global__ __launch_bounds__(256) void k_scatter(
    const int* __restrict__ src, const int* __restrict__ dst,
    const float* __restrict__ asrc, const float* __restrict__ adst,
    const float* __restrict__ ba_p, const unsigned* __restrict__ m_enc,
    const float* __restrict__ denom, const float* __restrict__ hw,
    float* __restrict__ out, int n_edges)
{
    long long t = (long long)blockIdx.x * 256 + threadIdx.x;
    int e = (int)(t >> 6);
    if (e >= n_edges) return;
    int c = (int)(t & 63);
    int hd = c >> 4;
    int s = src[e], d = dst[e];
    float a = asrc[(size_t)s * 4 + hd] + adst[(size_t)d * 4 + hd] + *ba_p;
    a = LRELU(a);
    float m = dec_f(m_enc[(size_t)d * 4 + hd]);
    float w = __expf(a - m) / denom[(size_t)d * 4 + hd];
    atomicAdd(out + (size_t)d * 64 + c, w * hw[(size_t)s * 64 + c]);
}

extern "C" void kernel_launch(void* const* d_in, const int* in_sizes, int n_in,
                              void* d_out, int out_size, void* d_ws, size_t ws_size,
                              hipStream_t stream)
{
    const float* h  = (const float*)d_in[0];
    const float* Ww = (const float*)d_in[1];
    const float* bw = (const float*)d_in[2];
    const float* Wa = (const float*)d_in[3];
    const float* ba = (const float*)d_in[4];
    const int* src  = (const int*)d_in[5];
    const int* dst  = (const int*)d_in[6];

    const int n_nodes = in_sizes[0] / 128;
    const int n_edges = in_sizes[5];

    // Workspace layout (floats): hw[N*64] | asrc[N*4] | adst[N*4] | m_enc[N*4] | denom[N*4]
    float* hw       = (float*)d_ws;
    float* asrc     = hw + (size_t)n_nodes * 64;
    float* adst     = asrc + (size_t)n_nodes * 4;
    unsigned* m_enc = (unsigned*)(adst + (size_t)n_nodes * 4);
    float* denom    = (float*)(m_enc + (size_t)n_nodes * 4);

    float* out = (float*)d_out;
    hipMemsetAsync(out, 0, (size_t)out_size * sizeof(float), stream);

    k_proj<<<(n_nodes + 31) / 32, 256, 0, stream>>>(h, Ww, bw, hw, n_nodes);
    k_node<<<(n_nodes * 4 + 255) / 256, 256, 0, stream>>>(hw, Wa, asrc, adst, m_enc, denom, n_nodes * 4);
    k_edge_max<<<(n_edges + 255) / 256, 256, 0, stream>>>(src, dst, asrc, adst, ba, m_enc, n_edges);
    k_edge_sum<<<(n_edges + 255) / 256, 256, 0, stream>>>(src, dst, asrc, adst, ba, m_enc, denom, n_edges);
    const int tot = n_edges * 64;  // 51.2M threads, one per (edge, col)
    k_scatter<<<(tot + 255) / 256, 256, 0, stream>>>(src, dst, asrc, adst, ba, m_enc, denom, hw, out, n_edges);
}

// Round 2
// 215.711 us; speedup vs baseline: 2.4059x; 2.4059x over previous
//
#include <hip/hip_runtime.h>

#define LRELU(x) ((x) > 0.f ? (x) : 0.01f * (x))

// hw[n, c] = dot(h[n, :], Ww[:, c]) + bw[c]   (N x 128) @ (128 x 64)
// 8 rows per wave; each thread: 2 cols x 4 rows. Ww staged in LDS.
__global__ __launch_bounds__(256) void k_proj(
    const float* __restrict__ h, const float* __restrict__ Ww,
    const float* __restrict__ bw, float* __restrict__ hw, int n_nodes)
{
    __shared__ float ws[128 * 64];
#pragma unroll
    for (int i = 0; i < 32; ++i)
        ws[i * 256 + threadIdx.x] = Ww[i * 256 + threadIdx.x];
    __syncthreads();

    const int lane = threadIdx.x & 63;
    const int wid  = threadIdx.x >> 6;
    const int cp   = lane & 31;   // column pair: cols 2cp, 2cp+1
    const int rsub = lane >> 5;   // 0/1: which 4-row half of the 8-row group
    const int row0 = (blockIdx.x * 4 + wid) * 8 + rsub * 4;
    if (row0 >= n_nodes) return;

    float acc[4][2] = {{0.f,0.f},{0.f,0.f},{0.f,0.f},{0.f,0.f}};
    const float* hrow = h + (size_t)row0 * 128;

    for (int k = 0; k < 128; k += 4) {
        float ha[4][4];
#pragma unroll
        for (int r = 0; r < 4; ++r)
            *(float4*)ha[r] = *(const float4*)(hrow + r * 128 + k);
#pragma unroll
        for (int kk = 0; kk < 4; ++kk) {
            float2 w2 = *(const float2*)(&ws[(k + kk) * 64 + cp * 2]);
#pragma unroll
            for (int r = 0; r < 4; ++r) {
                acc[r][0] = __fmaf_rn(ha[r][kk], w2.x, acc[r][0]);
                acc[r][1] = __fmaf_rn(ha[r][kk], w2.y, acc[r][1]);
            }
        }
    }
    const float b0 = bw[cp * 2], b1 = bw[cp * 2 + 1];
#pragma unroll
    for (int r = 0; r < 4; ++r) {
        float2 o;
        o.x = acc[r][0] + b0;
        o.y = acc[r][1] + b1;
        *(float2*)(hw + (size_t)(row0 + r) * 64 + cp * 2) = o;
    }
}

// Per (node, head): asrc = <hw[n,h,:], Wa[0:16]>, adst = <hw[n,h,:], Wa[16:32]> + ba
__global__ __launch_bounds__(256) void k_node(
    const float* __restrict__ hw, const float* __restrict__ Wa,
    const float* __restrict__ ba_p,
    float* __restrict__ asrc, float* __restrict__ adst, int n4)
{
    int i = blockIdx.x * 256 + threadIdx.x;
    if (i >= n4) return;
    const float* hp = hw + (size_t)i * 16;  // (n*4+hd)*16 == n*64 + hd*16
    float as = 0.f, ad = 0.f;
#pragma unroll
    for (int j = 0; j < 16; ++j) {
        float v = hp[j];
        as = __fmaf_rn(v, Wa[j], as);
        ad = __fmaf_rn(v, Wa[16 + j], ad);
    }
    asrc[i] = as;
    adst[i] = ad + *ba_p;
}

__global__ __launch_bounds__(256) void k_hist(
    const int* __restrict__ dst, int* __restrict__ counts, int n_edges)
{
    int e = blockIdx.x * 256 + threadIdx.x;
    if (e < n_edges) atomicAdd(&counts[dst[e]], 1);
}

// chunk_sum[c] = sum of counts[c*1024 .. c*1024+1023]
__global__ __launch_bounds__(256) void k_blocksum(
    const int* __restrict__ counts, int* __restrict__ chunk_sum, int n_nodes)
{
    __shared__ int red[256];
    int t = threadIdx.x;
    int base = blockIdx.x * 1024 + t * 4;
    int s = 0;
#pragma unroll
    for (int k = 0; k < 4; ++k)
        if (base + k < n_nodes) s += counts[base + k];
    red[t] = s;
    __syncthreads();
    for (int off = 128; off > 0; off >>= 1) {
        if (t < off) red[t] += red[t + off];
        __syncthreads();
    }
    if (t == 0) chunk_sum[blockIdx.x] = red[0];
}

// Exclusive scan of chunk sums (single wave, carry loop). Also writes row_start[N] = E.
__global__ __launch_bounds__(64) void k_chunkscan(
    const int* __restrict__ chunk_sum, int* __restrict__ chunk_off,
    int* __restrict__ row_start, int nch, int n_nodes)
{
    int lane = threadIdx.x;
    int carry = 0;
    for (int base = 0; base < nch; base += 64) {
        int t = base + lane;
        int orig = (t < nch) ? chunk_sum[t] : 0;
        int v = orig;
#pragma unroll
        for (int off = 1; off < 64; off <<= 1) {
            int n = __shfl_up(v, off);
            if (lane >= off) v += n;
        }
        if (t < nch) chunk_off[t] = carry + v - orig;
        carry += __shfl(v, 63);
    }
    if (lane == 0) row_start[n_nodes] = carry;
}

// Per-chunk exclusive scan -> row_start; also initializes cursor (in-place over counts).
__global__ __launch_bounds__(256) void k_localscan(
    int* __restrict__ counts /* becomes cursor */, const int* __restrict__ chunk_off,
    int* __restrict__ row_start, int n_nodes)
{
    __shared__ int wtot[4];
    int t = threadIdx.x;
    int lane = t & 63, wid = t >> 6;
    int base = blockIdx.x * 1024 + t * 4;
    int v[4];
    int s4 = 0;
#pragma unroll
    for (int k = 0; k < 4; ++k) {
        v[k] = (base + k < n_nodes) ? counts[base + k] : 0;
        s4 += v[k];
    }
    int inc = s4;
#pragma unroll
    for (int off = 1; off < 64; off <<= 1) {
        int n = __shfl_up(inc, off);
        if (lane >= off) inc += n;
    }
    if (lane == 63) wtot[wid] = inc;
    __syncthreads();
    int wpre = 0;
    for (int w = 0; w < wid; ++w) wpre += wtot[w];
    int running = chunk_off[blockIdx.x] + wpre + inc - s4;  // exclusive prefix
#pragma unroll
    for (int k = 0; k < 4; ++k) {
        if (base + k < n_nodes) {
            row_start[base + k] = running;
            counts[base + k] = running;  // cursor init
        }
        running += v[k];
    }
}

// Scatter edges into CSR slots: esrc[pos] = src[e]
__global__ __launch_bounds__(256) void k_fill(
    const int* __restrict__ src, const int* __restrict__ dst,
    int* __restrict__ cursor, int* __restrict__ esrc, int n_edges)
{
    int e = blockIdx.x * 256 + threadIdx.x;
    if (e >= n_edges) return;
    int d = dst[e];
    int pos = atomicAdd(&cursor[d], 1);
    esrc[pos] = src[e];
}

// One wave per dst node; lane = output col; single fused softmax+weighted-sum pass.
__global__ __launch_bounds__(256) void k_gather(
    const int* __restrict__ esrc, const int* __restrict__ row_start,
    const float* __restrict__ asrc, const float* __restrict__ adst,
    const float* __restrict__ hw, float* __restrict__ out, int n_nodes)
{
    int d = blockIdx.x * 4 + (threadIdx.x >> 6);
    if (d >= n_nodes) return;
    int lane = threadIdx.x & 63;
    int head = lane >> 4;
    int start = row_start[d], end = row_start[d + 1];
    float ad = adst[(size_t)d * 4 + head];
    float acc = 0.f, den = 0.f;
    for (int i = start; i < end; ++i) {
        int s = esrc[i];
        float a = asrc[(size_t)s * 4 + head] + ad;
        a = LRELU(a);
        float ea = __expf(a);
        den += ea;
        acc = __fmaf_rn(ea, hw[(size_t)s * 64 + lane], acc);
    }
    out[(size_t)d * 64 + lane] = (end > start) ? acc / den : 0.f;
}

extern "C" void kernel_launch(void* const* d_in, const int* in_sizes, int n_in,
                              void* d_out, int out_size, void* d_ws, size_t ws_size,
                              hipStream_t stream)
{
    const float* h  = (const float*)d_in[0];
    const float* Ww = (const float*)d_in[1];
    const float* bw = (const float*)d_in[2];
    const float* Wa = (const float*)d_in[3];
    const float* ba = (const float*)d_in[4];
    const int* src  = (const int*)d_in[5];
    const int* dst  = (const int*)d_in[6];

    const int n_nodes = in_sizes[0] / 128;
    const int n_edges = in_sizes[5];
    const int nch = (n_nodes + 1023) / 1024;

    // Workspace (4B words):
    // hw[N*64] | asrc[N*4] | adst[N*4] | counts/cursor[N] | row_start[N+1] |
    // chunk_sum[nch] | chunk_off[nch] | esrc[E]
    float* hw      = (float*)d_ws;
    float* asrc    = hw + (size_t)n_nodes * 64;
    float* adst    = asrc + (size_t)n_nodes * 4;
    int* counts    = (int*)(adst + (size_t)n_nodes * 4);
    int* row_start = counts + n_nodes;
    int* chunk_sum = row_start + n_nodes + 1;
    int* chunk_off = chunk_sum + nch;
    int* esrc      = chunk_off + nch;

    float* out = (float*)d_out;

    hipMemsetAsync(counts, 0, (size_t)n_nodes * sizeof(int), stream);

    k_proj<<<(n_nodes + 31) / 32, 256, 0, stream>>>(h, Ww, bw, hw, n_nodes);
    k_node<<<(n_nodes * 4 + 255) / 256, 256, 0, stream>>>(hw, Wa, ba, asrc, adst, n_nodes * 4);
    k_hist<<<(n_edges + 255) / 256, 256, 0, stream>>>(dst, counts, n_edges);
    k_blocksum<<<nch, 256, 0, stream>>>(counts, chunk_sum, n_nodes);
    k_chunkscan<<<1, 64, 0, stream>>>(chunk_sum, chunk_off, row_start, nch, n_nodes);
    k_localscan<<<nch, 256, 0, stream>>>(counts, chunk_off, row_start, n_nodes);
    k_fill<<<(n_edges + 255) / 256, 256, 0, stream>>>(src, dst, counts, esrc, n_edges);
    k_gather<<<(n_nodes + 3) / 4, 256, 0, stream>>>(esrc, row_start, asrc, adst, hw, out, n_nodes);
}